// Round 5
// baseline (205.011 us; speedup 1.0000x reference)
//
#include <hip/hip_runtime.h>
#include <hip/hip_bf16.h>
#include <math.h>

#define BB   16
#define CIN  256
#define HH   64
#define WW   64
#define COUT 256
#define NEXP 4
#define REDC 16
#define HW   (HH*WW)       // 4096

typedef __attribute__((ext_vector_type(8))) short short8;
typedef __attribute__((ext_vector_type(4))) float f32x4;

#define AS1 __attribute__((address_space(1)))
#define AS3 __attribute__((address_space(3)))

__device__ __forceinline__ void gld_lds16(void* lds, const void* gp) {
    __builtin_amdgcn_global_load_lds((const AS1 unsigned int*)gp,
                                     (AS3 unsigned int*)lds, 16, 0, 0);
}

// -------- K0: x (f32, [b][c][s]) -> xT (bf16, [b][s][c]) + pooled partials --------
__global__ __launch_bounds__(256)
void transpose_pool_kernel(const float* __restrict__ x, ushort* __restrict__ xT,
                           float* __restrict__ pp) {
    int blk = blockIdx.x;
    int sq = blk & 3;
    int chunk = (blk >> 2) & 7;
    int b = blk >> 5;
    int c0 = chunk * 32;
    int s0 = sq * 1024;
    int tid = threadIdx.x;
    const float* xb = x + ((size_t)(b * CIN + c0)) * HW;
    ushort* xTb = xT + (size_t)b * HW * CIN;

    float psum[32];
    #pragma unroll
    for (int i = 0; i < 32; ++i) psum[i] = 0.f;

    for (int it = 0; it < 4; ++it) {
        int s = s0 + it * 256 + tid;
        unsigned int pk[16];
        #pragma unroll
        for (int p = 0; p < 16; ++p) {
            float lo = xb[(size_t)(2 * p) * HW + s];
            float hi = xb[(size_t)(2 * p + 1) * HW + s];
            psum[2 * p]     += lo;
            psum[2 * p + 1] += hi;
            asm volatile("v_cvt_pk_bf16_f32 %0, %1, %2" : "=v"(pk[p]) : "v"(lo), "v"(hi));
        }
        uint4* dst = (uint4*)(xTb + (size_t)s * CIN + c0);
        #pragma unroll
        for (int q = 0; q < 4; ++q)
            dst[q] = make_uint4(pk[q * 4], pk[q * 4 + 1], pk[q * 4 + 2], pk[q * 4 + 3]);
    }

    __shared__ float red[4][32];
    int lane = tid & 63, wid = tid >> 6;
    #pragma unroll
    for (int i = 0; i < 32; ++i) {
        float v = psum[i];
        #pragma unroll
        for (int off = 32; off > 0; off >>= 1) v += __shfl_down(v, off, 64);
        if (lane == 0) red[wid][i] = v;
    }
    __syncthreads();
    if (tid < 32)
        pp[(b * 4 + sq) * 256 + c0 + tid] = red[0][tid] + red[1][tid] + red[2][tid] + red[3][tid];
}

// ---------------- K2: routing MLP -> rw[b*1024 + k*256 + c] ----------------
__global__ void route_kernel(const float* __restrict__ pp,
                             const float* __restrict__ w1, const float* __restrict__ b1,
                             const float* __restrict__ w2, const float* __restrict__ b2,
                             float* __restrict__ rw) {
    __shared__ float p_s[BB][CIN];
    __shared__ float r_s[BB][REDC];
    int tid = threadIdx.x;
    for (int i = tid; i < BB * CIN; i += 256) {
        int b = i >> 8, c = i & 255;
        p_s[b][c] = (pp[(b * 4 + 0) * 256 + c] + pp[(b * 4 + 1) * 256 + c] +
                     pp[(b * 4 + 2) * 256 + c] + pp[(b * 4 + 3) * 256 + c]) * (1.0f / HW);
    }
    __syncthreads();
    {
        int b = tid >> 4, j = tid & 15;
        float acc = b1[j];
        for (int c = 0; c < CIN; ++c) acc += p_s[b][c] * w1[j * CIN + c];
        r_s[b][j] = fmaxf(acc, 0.f);
    }
    __syncthreads();
    for (int i = tid; i < BB * NEXP * CIN; i += 256) {
        int b = i >> 10, o2 = i & 1023;
        float acc = b2[o2];
        #pragma unroll
        for (int j = 0; j < REDC; ++j) acc += r_s[b][j] * w2[o2 * REDC + j];
        rw[i] = 1.f / (1.f + expf(-acc));
    }
}

// ------- K3 v2: combined weights, exactly-once coalesced weight reads -------
// grid: 128 blocks = oq(4) x chunk(8) x ot(4). Each block owns a weight slice
// [4k][16o][32c][9t] read as contiguous 288-float runs, staged via LDS in
// 4-o batches. Output layout unchanged (conv fragment order).
__global__ __launch_bounds__(256)
void combine2_kernel(const float* __restrict__ rw,
                     const float* __restrict__ weight,
                     ushort* __restrict__ cw) {
    int blk = blockIdx.x;
    int oq    = blk & 3;
    int chunk = (blk >> 2) & 7;
    int ot    = blk >> 5;
    int tid = threadIdx.x;

    __shared__ float ws_s[4][4][288];   // [k][oo][c*9+t9]  18432 B
    __shared__ float rw_s[4 * 32 * 16]; // [k][c][b]         8192 B

    for (int i = tid; i < 2048; i += 256) {
        int b = i >> 7, r = i & 127, k = r >> 5, cc = r & 31;
        rw_s[k * 512 + cc * 16 + b] = rw[b * 1024 + k * 256 + chunk * 32 + cc];
    }
    __syncthreads();

    int b = tid >> 4, low = tid & 15;

    for (int batch = 0; batch < 4; ++batch) {
        // stage 16 rows (k x oo) of 288 contiguous floats, fully coalesced
        #pragma unroll
        for (int r = 0; r < 16; ++r) {
            int k = r >> 2, oo = r & 3;
            const float* wrow = weight +
                ((size_t)(k * COUT + ot * 64 + oq * 16 + batch * 4 + oo) * CIN
                 + chunk * 32) * 9;
            for (int e = tid; e < 288; e += 256) ws_s[k][oo][e] = wrow[e];
        }
        __syncthreads();

        #pragma unroll
        for (int t9 = 0; t9 < 9; ++t9) {
            #pragma unroll
            for (int g = 0; g < 4; ++g) {
                #pragma unroll
                for (int rep = 0; rep < 2; ++rep) {
                    int slot = rep * 16 + low;       // 0..31 = oo*8 + c8
                    int oo = slot >> 3, c8 = slot & 7;
                    int c = g * 8 + c8;
                    float acc = 0.f;
                    #pragma unroll
                    for (int k = 0; k < 4; ++k)
                        acc += rw_s[k * 512 + c * 16 + b] * ws_s[k][oo][c * 9 + t9];
                    __hip_bfloat16 hv = __float2bfloat16(acc);
                    size_t idx = (((size_t)((b * 4 + ot) * 8 + chunk) * 9 + t9) * 4 + g) * 512
                                 + (oq * 16 + batch * 4 + oo) * 8 + c8;
                    cw[idx] = *(ushort*)&hv;
                }
            }
        }
        __syncthreads();
    }
}

// ---------------- K4: MFMA implicit-GEMM conv, A direct from global ----------------
// block: 256 thr (4 waves), 2-phase (R3 structure). LDS holds ONLY the x tile
// (42 KB). A-frags load per-tap straight from cw (coalesced 256B segments,
// L1/L2-resident: slice shared by all 4 waves + 8 row-blocks).
__global__ __launch_bounds__(256, 2)
void conv_mfma(const ushort* __restrict__ xT, const ushort* __restrict__ cw,
               float* __restrict__ out) {
    __shared__ unsigned int xs[10560];   // 660 s * 16 words = 42240 B

    int hw = blockIdx.x;
    int L = (hw & 7) * 64 + (hw >> 3);   // XCD-chunked swizzle (512 = 8*64)
    int b  = L >> 5;
    int rt = (L >> 2) & 7;
    int ot = L & 3;
    int r0 = rt * 8, o0 = ot * 64;
    int tid  = threadIdx.x;
    int lane = tid & 63, wid = tid >> 6;
    int l15  = lane & 15, g = lane >> 4;

    for (int i = tid; i < 10560; i += 256) xs[i] = 0;

    f32x4 acc[4][8];
    #pragma unroll
    for (int mi = 0; mi < 4; ++mi)
        #pragma unroll
        for (int f = 0; f < 8; ++f) acc[mi][f] = (f32x4)0.f;

    const ushort* xTb = xT + (size_t)b * HW * CIN;
    const char*   Ab  = (const char*)cw + (size_t)((b * 4 + ot) * 8) * 36864;

    __syncthreads();

    for (int chunk = 0; chunk < 8; ++chunk) {
        // ---- stage x: 10 rows x 4 col-quarters, 1 KB per gld ----
        #pragma unroll
        for (int i = 0; i < 10; ++i) {
            int q = i * 4 + wid;             // wave-uniform 0..39
            int r = q >> 2, cq = q & 3;
            int grow = r0 - 1 + r;
            if (grow >= 0 && grow < 64) {
                int sbase = r * 66 + 1 + cq * 16;
                int s_l   = sbase + (lane >> 2);
                int sigma = (lane & 3) ^ ((s_l >> 1) & 3);
                const ushort* src = xTb
                    + (size_t)(grow * 64 + cq * 16 + (lane >> 2)) * CIN
                    + chunk * 32 + sigma * 8;
                gld_lds16(&xs[sbase * 16], src);
            }
        }
        __syncthreads();

        const char* Acb = Ab + (size_t)chunk * 36864;
        int wrow = wid * 2;
        #pragma unroll
        for (int t9 = 0; t9 < 9; ++t9) {
            int di = t9 / 3, dj = t9 - di * 3;
            const short8* ap = (const short8*)(Acb + ((t9 * 4 + g) << 10) + (l15 << 4));
            short8 a0 = ap[0];
            short8 a1 = ap[16];
            short8 a2 = ap[32];
            short8 a3 = ap[48];
            #pragma unroll
            for (int f = 0; f < 8; ++f) {
                int s = (wrow + (f >> 2) + di) * 66 + (f & 3) * 16 + l15 + dj;
                short8 bb = *(short8*)&xs[s * 16 + ((g ^ ((s >> 1) & 3)) << 2)];
                acc[0][f] = __builtin_amdgcn_mfma_f32_16x16x32_bf16(a0, bb, acc[0][f], 0, 0, 0);
                acc[1][f] = __builtin_amdgcn_mfma_f32_16x16x32_bf16(a1, bb, acc[1][f], 0, 0, 0);
                acc[2][f] = __builtin_amdgcn_mfma_f32_16x16x32_bf16(a2, bb, acc[2][f], 0, 0, 0);
                acc[3][f] = __builtin_amdgcn_mfma_f32_16x16x32_bf16(a3, bb, acc[3][f], 0, 0, 0);
            }
        }
        __syncthreads();
    }

    // ---- epilogue ----
    #pragma unroll
    for (int mi = 0; mi < 4; ++mi) {
        #pragma unroll
        for (int f = 0; f < 8; ++f) {
            int pos = (r0 + wid * 2 + (f >> 2)) * 64 + (f & 3) * 16 + l15;
            float* op = out + ((size_t)(b * COUT + o0 + mi * 16 + g * 4)) * HW + pos;
            #pragma unroll
            for (int j = 0; j < 4; ++j) op[(size_t)j * HW] = acc[mi][f][j];
        }
    }
}

extern "C" void kernel_launch(void* const* d_in, const int* in_sizes, int n_in,
                              void* d_out, int out_size, void* d_ws, size_t ws_size,
                              hipStream_t stream) {
    const float* x      = (const float*)d_in[0];
    const float* w1     = (const float*)d_in[1];
    const float* b1     = (const float*)d_in[2];
    const float* w2     = (const float*)d_in[3];
    const float* b2     = (const float*)d_in[4];
    const float* weight = (const float*)d_in[5];
    float* out = (float*)d_out;

    float*  ws = (float*)d_ws;
    float*  pp = ws;                              // 16384 f
    float*  rw = ws + 16384;                      // 16384 f
    ushort* cw = (ushort*)(ws + 32768);           // 9437184 ushort (~18.9 MB)
    ushort* xT = (ushort*)(ws + 32768 + 4718592); // 16777216 ushort (~33.6 MB)

    transpose_pool_kernel<<<512, 256, 0, stream>>>(x, xT, pp);
    route_kernel<<<1, 256, 0, stream>>>(pp, w1, b1, w2, b2, rw);
    combine2_kernel<<<128, 256, 0, stream>>>(rw, weight, cw);
    conv_mfma<<<512, 256, 0, stream>>>(xT, cw, out);
}

// Round 6
// 199.279 us; speedup vs baseline: 1.0288x; 1.0288x over previous
//
#include <hip/hip_runtime.h>
#include <hip/hip_bf16.h>
#include <math.h>

#define BB   16
#define CIN  256
#define HH   64
#define WW   64
#define COUT 256
#define NEXP 4
#define REDC 16
#define HW   (HH*WW)       // 4096

typedef __attribute__((ext_vector_type(8))) short short8;
typedef __attribute__((ext_vector_type(4))) float f32x4;
typedef __attribute__((ext_vector_type(16))) float f32x16;

#define AS1 __attribute__((address_space(1)))
#define AS3 __attribute__((address_space(3)))

__device__ __forceinline__ void gld_lds16(void* lds, const void* gp) {
    __builtin_amdgcn_global_load_lds((const AS1 unsigned int*)gp,
                                     (AS3 unsigned int*)lds, 16, 0, 0);
}

// -------- K0: x (f32, [b][c][s]) -> xT (bf16, [b][s][c]) + pooled partials --------
__global__ __launch_bounds__(256)
void transpose_pool_kernel(const float* __restrict__ x, ushort* __restrict__ xT,
                           float* __restrict__ pp) {
    int blk = blockIdx.x;
    int sq = blk & 3;
    int chunk = (blk >> 2) & 7;
    int b = blk >> 5;
    int c0 = chunk * 32;
    int s0 = sq * 1024;
    int tid = threadIdx.x;
    const float* xb = x + ((size_t)(b * CIN + c0)) * HW;
    ushort* xTb = xT + (size_t)b * HW * CIN;

    float psum[32];
    #pragma unroll
    for (int i = 0; i < 32; ++i) psum[i] = 0.f;

    for (int it = 0; it < 4; ++it) {
        int s = s0 + it * 256 + tid;
        unsigned int pk[16];
        #pragma unroll
        for (int p = 0; p < 16; ++p) {
            float lo = xb[(size_t)(2 * p) * HW + s];
            float hi = xb[(size_t)(2 * p + 1) * HW + s];
            psum[2 * p]     += lo;
            psum[2 * p + 1] += hi;
            asm volatile("v_cvt_pk_bf16_f32 %0, %1, %2" : "=v"(pk[p]) : "v"(lo), "v"(hi));
        }
        uint4* dst = (uint4*)(xTb + (size_t)s * CIN + c0);
        #pragma unroll
        for (int q = 0; q < 4; ++q)
            dst[q] = make_uint4(pk[q * 4], pk[q * 4 + 1], pk[q * 4 + 2], pk[q * 4 + 3]);
    }

    __shared__ float red[4][32];
    int lane = tid & 63, wid = tid >> 6;
    #pragma unroll
    for (int i = 0; i < 32; ++i) {
        float v = psum[i];
        #pragma unroll
        for (int off = 32; off > 0; off >>= 1) v += __shfl_down(v, off, 64);
        if (lane == 0) red[wid][i] = v;
    }
    __syncthreads();
    if (tid < 32)
        pp[(b * 4 + sq) * 256 + c0 + tid] = red[0][tid] + red[1][tid] + red[2][tid] + red[3][tid];
}

// ---------------- K2: routing MLP -> rw[b*1024 + k*256 + c] ----------------
__global__ void route_kernel(const float* __restrict__ pp,
                             const float* __restrict__ w1, const float* __restrict__ b1,
                             const float* __restrict__ w2, const float* __restrict__ b2,
                             float* __restrict__ rw) {
    __shared__ float p_s[BB][CIN];
    __shared__ float r_s[BB][REDC];
    int tid = threadIdx.x;
    for (int i = tid; i < BB * CIN; i += 256) {
        int b = i >> 8, c = i & 255;
        p_s[b][c] = (pp[(b * 4 + 0) * 256 + c] + pp[(b * 4 + 1) * 256 + c] +
                     pp[(b * 4 + 2) * 256 + c] + pp[(b * 4 + 3) * 256 + c]) * (1.0f / HW);
    }
    __syncthreads();
    {
        int b = tid >> 4, j = tid & 15;
        float acc = b1[j];
        for (int c = 0; c < CIN; ++c) acc += p_s[b][c] * w1[j * CIN + c];
        r_s[b][j] = fmaxf(acc, 0.f);
    }
    __syncthreads();
    for (int i = tid; i < BB * NEXP * CIN; i += 256) {
        int b = i >> 10, o2 = i & 1023;
        float acc = b2[o2];
        #pragma unroll
        for (int j = 0; j < REDC; ++j) acc += r_s[b][j] * w2[o2 * REDC + j];
        rw[i] = 1.f / (1.f + expf(-acc));
    }
}

// ------- K3: combined weights, exactly-once coalesced weight reads -------
// Output layout (16-channel chunks, for conv A-frags):
//   idx = ((((b*4+ot)*16 + chunk16)*9 + t9)*2 + g)*512 + o_loc*8 + c8
//   where c = chunk16*16 + g*8 + c8, o = ot*64 + o_loc.
__global__ __launch_bounds__(256)
void combine2_kernel(const float* __restrict__ rw,
                     const float* __restrict__ weight,
                     ushort* __restrict__ cw) {
    int blk = blockIdx.x;
    int oq    = blk & 3;
    int chunk = (blk >> 2) & 7;   // 32-channel chunk
    int ot    = blk >> 5;
    int tid = threadIdx.x;

    __shared__ float ws_s[4][4][288];   // [k][oo][c*9+t9]
    __shared__ float rw_s[4 * 32 * 16]; // [k][c][b]

    for (int i = tid; i < 2048; i += 256) {
        int b = i >> 7, r = i & 127, k = r >> 5, cc = r & 31;
        rw_s[k * 512 + cc * 16 + b] = rw[b * 1024 + k * 256 + chunk * 32 + cc];
    }
    __syncthreads();

    int b = tid >> 4, low = tid & 15;

    for (int batch = 0; batch < 4; ++batch) {
        #pragma unroll
        for (int r = 0; r < 16; ++r) {
            int k = r >> 2, oo = r & 3;
            const float* wrow = weight +
                ((size_t)(k * COUT + ot * 64 + oq * 16 + batch * 4 + oo) * CIN
                 + chunk * 32) * 9;
            for (int e = tid; e < 288; e += 256) ws_s[k][oo][e] = wrow[e];
        }
        __syncthreads();

        #pragma unroll
        for (int t9 = 0; t9 < 9; ++t9) {
            #pragma unroll
            for (int g = 0; g < 4; ++g) {
                #pragma unroll
                for (int rep = 0; rep < 2; ++rep) {
                    int slot = rep * 16 + low;       // 0..31 = oo*8 + c8
                    int oo = slot >> 3, c8 = slot & 7;
                    int c = g * 8 + c8;
                    float acc = 0.f;
                    #pragma unroll
                    for (int k = 0; k < 4; ++k)
                        acc += rw_s[k * 512 + c * 16 + b] * ws_s[k][oo][c * 9 + t9];
                    __hip_bfloat16 hv = __float2bfloat16(acc);
                    int chunk16 = chunk * 2 + (g >> 1);
                    int gg = g & 1;
                    size_t idx = ((((size_t)(b * 4 + ot) * 16 + chunk16) * 9 + t9) * 2 + gg) * 512
                                 + (oq * 16 + batch * 4 + oo) * 8 + c8;
                    cw[idx] = *(ushort*)&hv;
                }
            }
        }
        __syncthreads();
    }
}

// ---------------- K4: MFMA conv, 32x32x16, dbuf + counted vmcnt ----------------
// 256 blocks x 512 thr (8 waves, 2/SIMD). block = 64 o x 16 rows.
// 16 chunks x 16 channels. LDS: dbuf A (18432 B) + X (38912 B) = 114688 B.
// Per chunk each wave issues exactly 7 global_load_lds -> s_waitcnt vmcnt(7).
__global__ __launch_bounds__(512, 2)
void conv_mfma(const ushort* __restrict__ xT, const ushort* __restrict__ cw,
               float* __restrict__ out, const ushort* __restrict__ zp) {
    __shared__ ushort As[2][9216];    // [t9][g2][o64][c8]
    __shared__ ushort Xs[2][19456];   // 1216 s * 16 c  (s = r*66 + cc, r 0..17+pad)

    int blk = blockIdx.x;
    int L = (blk & 7) * 32 + (blk >> 3);   // XCD-chunked swizzle (256 = 8*32)
    int b  = L >> 4;
    int rt = (L >> 2) & 3;
    int ot = L & 3;
    int r0 = rt * 16, o0 = ot * 64;
    int tid = threadIdx.x;
    int lane = tid & 63, wid = tid >> 6;
    int l31 = lane & 31, h = lane >> 5;

    f32x16 acc[2][4];
    #pragma unroll
    for (int mi = 0; mi < 2; ++mi)
        #pragma unroll
        for (int f = 0; f < 4; ++f) acc[mi][f] = (f32x16)0.f;

    const ushort* xTb = xT + (size_t)b * HW * CIN;
    const ushort* Ab  = cw + (size_t)((b * 4 + ot) * 16) * 9216;  // per chunk 9216 ushorts

    // ---- stage(bufsel, chunk): 7 gld_lds16 per wave ----
    #define STAGE(BUF, CH)                                                      \
    {                                                                           \
        int ch_ = (CH);                                                         \
        _Pragma("unroll")                                                       \
        for (int i = 0; i < 7; ++i) {                                           \
            int u = wid * 7 + i;                                                \
            if (u < 18) {                                                       \
                gld_lds16(&As[BUF][u * 512],                                    \
                          Ab + (size_t)ch_ * 9216 + u * 512 + lane * 8);        \
            } else {                                                            \
                int up = u - 18;                                                \
                int s  = up * 32 + (lane >> 1);                                 \
                int r  = (unsigned)s / 66u;                                     \
                int cc = s - r * 66;                                            \
                int grow = r0 - 1 + r;                                          \
                const ushort* src;                                              \
                if (cc == 0 || cc == 65 || grow < 0 || grow > 63 || r > 17)     \
                    src = zp + lane * 8;                                        \
                else                                                            \
                    src = xTb + (size_t)(grow * 64 + cc - 1) * CIN              \
                              + ch_ * 16 + (lane & 1) * 8;                      \
                gld_lds16(&Xs[BUF][up * 512], src);                             \
            }                                                                   \
        }                                                                       \
    }

    // prologue: stage chunk 0 into buffer 0
    STAGE(0, 0)

    #pragma unroll 1
    for (int chunk = 0; chunk < 16; ++chunk) {
        int cur = chunk & 1;
        if (chunk < 15) {
            STAGE(cur ^ 1, chunk + 1)
            asm volatile("s_waitcnt vmcnt(7)" ::: "memory");
        } else {
            asm volatile("s_waitcnt vmcnt(0)" ::: "memory");
        }
        __builtin_amdgcn_s_barrier();
        __builtin_amdgcn_sched_barrier(0);

        const ushort* asb = &As[cur][0];
        const ushort* xsb = &Xs[cur][0];
        #pragma unroll
        for (int t9 = 0; t9 < 9; ++t9) {
            int di = t9 / 3, dj = t9 - di * 3;
            short8 a0 = *(short8*)&asb[((t9 * 2 + h) * 64 + 0  + l31) * 8];
            short8 a1 = *(short8*)&asb[((t9 * 2 + h) * 64 + 32 + l31) * 8];
            short8 b0, b1v, b2v, b3;
            {
                int rr = wid * 2 + di;
                b0  = *(short8*)&xsb[(rr * 66 +  0 + l31 + dj) * 16 + h * 8];
                b1v = *(short8*)&xsb[(rr * 66 + 32 + l31 + dj) * 16 + h * 8];
                b2v = *(short8*)&xsb[((rr + 1) * 66 +  0 + l31 + dj) * 16 + h * 8];
                b3  = *(short8*)&xsb[((rr + 1) * 66 + 32 + l31 + dj) * 16 + h * 8];
            }
            __builtin_amdgcn_s_setprio(1);
            acc[0][0] = __builtin_amdgcn_mfma_f32_32x32x16_bf16(a0, b0,  acc[0][0], 0, 0, 0);
            acc[1][0] = __builtin_amdgcn_mfma_f32_32x32x16_bf16(a1, b0,  acc[1][0], 0, 0, 0);
            acc[0][1] = __builtin_amdgcn_mfma_f32_32x32x16_bf16(a0, b1v, acc[0][1], 0, 0, 0);
            acc[1][1] = __builtin_amdgcn_mfma_f32_32x32x16_bf16(a1, b1v, acc[1][1], 0, 0, 0);
            acc[0][2] = __builtin_amdgcn_mfma_f32_32x32x16_bf16(a0, b2v, acc[0][2], 0, 0, 0);
            acc[1][2] = __builtin_amdgcn_mfma_f32_32x32x16_bf16(a1, b2v, acc[1][2], 0, 0, 0);
            acc[0][3] = __builtin_amdgcn_mfma_f32_32x32x16_bf16(a0, b3,  acc[0][3], 0, 0, 0);
            acc[1][3] = __builtin_amdgcn_mfma_f32_32x32x16_bf16(a1, b3,  acc[1][3], 0, 0, 0);
            __builtin_amdgcn_s_setprio(0);
        }
        __builtin_amdgcn_sched_barrier(0);
        __builtin_amdgcn_s_barrier();   // all waves done reading buf cur
    }

    // ---- epilogue: C 32x32 layout: col(pos)=l31, row(o)=(j&3)+8*(j>>2)+4*h ----
    #pragma unroll
    for (int mi = 0; mi < 2; ++mi) {
        #pragma unroll
        for (int f = 0; f < 4; ++f) {
            int pos = (r0 + wid * 2 + (f >> 1)) * 64 + (f & 1) * 32 + l31;
            #pragma unroll
            for (int j = 0; j < 16; ++j) {
                int orow = (j & 3) + 8 * (j >> 2) + 4 * h;
                out[((size_t)(b * COUT + o0 + mi * 32 + orow)) * HW + pos] = acc[mi][f][j];
            }
        }
    }
    #undef STAGE
}

extern "C" void kernel_launch(void* const* d_in, const int* in_sizes, int n_in,
                              void* d_out, int out_size, void* d_ws, size_t ws_size,
                              hipStream_t stream) {
    const float* x      = (const float*)d_in[0];
    const float* w1     = (const float*)d_in[1];
    const float* b1     = (const float*)d_in[2];
    const float* w2     = (const float*)d_in[3];
    const float* b2     = (const float*)d_in[4];
    const float* weight = (const float*)d_in[5];
    float* out = (float*)d_out;

    float*  ws = (float*)d_ws;
    float*  pp = ws;                              // 16384 f
    float*  rw = ws + 16384;                      // 16384 f
    ushort* cw = (ushort*)(ws + 32768);           // 9437184 ushort (~18.9 MB)
    ushort* xT = (ushort*)(ws + 32768 + 4718592); // 16777216 ushort (~33.6 MB)
    ushort* zp = xT + 16777216;                   // 512 ushort zero page (1 KB)

    hipMemsetAsync(zp, 0, 1024, stream);
    transpose_pool_kernel<<<512, 256, 0, stream>>>(x, xT, pp);
    route_kernel<<<1, 256, 0, stream>>>(pp, w1, b1, w2, b2, rw);
    combine2_kernel<<<128, 256, 0, stream>>>(rw, weight, cw);
    conv_mfma<<<256, 512, 0, stream>>>(xT, cw, out, zp);
}